// Round 2
// baseline (121.412 us; speedup 1.0000x reference)
//
#include <hip/hip_runtime.h>
#include <stdint.h>

// ---------------------------------------------------------------------------
// DetectorKmeans: out[n] = sum_k (pr[k]*var[k]) / ||X[n]-C[k]||^2  - threshold
// N=65536, K=1024, D=512, all fp32 in/out.
// Round 14: the kernel is STAGING-RATE bound (R12: 10.6 B/cyc/CU, R13 showed
// rate rises with overlap but bytes matter more). Keep the byte-minimal
// 512-thr 256x256 geometry (512 MB staged total) and raise the rate via
// counted vmcnt + deep prefetch: BK=32 -> 32 KB slots, FOUR slots (128 KB),
// prefetch distance 3, steady-state wait vmcnt(8) (never 0 until tail).
// m97/m201 sustained 19-22 B/cyc/CU with this pattern vs our 10.6.
// ---------------------------------------------------------------------------

#define NR 65536
#define KC 1024
#define DD 512

#define BM 256
#define BN 256
#define BK 32
#define NKT (DD / BK)     // 16 K-tiles
#define NPART (KC / BN)   // 4 column panels

#define SLOT_SZ 32768     // A 256x32x2 (16 KB) + B 256x32x2 (16 KB)
#define PART_OFF 131072   // after 4 slots
#define LDS_TOTAL (PART_OFF + 4096)   // + [4][256] f32 partial = 135168 B

typedef __bf16 bf16;
typedef __attribute__((ext_vector_type(4))) __bf16 bf16x4;
typedef __attribute__((ext_vector_type(8))) __bf16 bf16x8;
typedef __attribute__((ext_vector_type(4))) float f32x4;

__device__ __forceinline__ void gload16(const void* g, void* l) {
  __builtin_amdgcn_global_load_lds(
      (const __attribute__((address_space(1))) unsigned int*)g,
      (__attribute__((address_space(3))) unsigned int*)l, 16, 0, 0);
}

// ---------------------------------------------------------------------------
__global__ __launch_bounds__(256) void prep_kernel(
    const float* __restrict__ X, const float* __restrict__ C,
    const float* __restrict__ var, const float* __restrict__ pr,
    bf16* __restrict__ Xb, bf16* __restrict__ Cb,
    float* __restrict__ xsq, float* __restrict__ csq, float* __restrict__ w) {
  const int row  = (int)((blockIdx.x * 256 + threadIdx.x) >> 6);
  const int lane = (int)(threadIdx.x & 63);
  const bool isX = row < NR;
  const float* srow = isX ? (X + (size_t)row * DD) : (C + (size_t)(row - NR) * DD);
  bf16* drow = isX ? (Xb + (size_t)row * DD) : (Cb + (size_t)(row - NR) * DD);

  float4 a = reinterpret_cast<const float4*>(srow)[lane];
  float4 b = reinterpret_cast<const float4*>(srow)[64 + lane];
  float s = a.x * a.x + a.y * a.y + a.z * a.z + a.w * a.w +
            b.x * b.x + b.y * b.y + b.z * b.z + b.w * b.w;
#pragma unroll
  for (int off = 1; off < 64; off <<= 1) s += __shfl_xor(s, off, 64);

  bf16x4 va = {(bf16)a.x, (bf16)a.y, (bf16)a.z, (bf16)a.w};
  bf16x4 vb = {(bf16)b.x, (bf16)b.y, (bf16)b.z, (bf16)b.w};
  reinterpret_cast<bf16x4*>(drow)[lane]      = va;
  reinterpret_cast<bf16x4*>(drow)[64 + lane] = vb;

  if (lane == 0) {
    if (isX) {
      xsq[row] = s;
    } else {
      const int k = row - NR;
      csq[k] = s;
      w[k]   = pr[k] * var[k];
    }
  }
}

// ---------------------------------------------------------------------------
// LDS per 32 KB slot:
//   A at [0, 16384):     256 rows x 64 B (BK=32); row r's 16-B chunk c lives
//                        at slot c ^ ((r>>1)&3)  (2-way-free b128 reads).
//   B at [16384, 32768): 256 cols x 64 B, same chunk swizzle.
//   Pre-swizzled gload source, linear DMA dest (wave-uniform base + lane*16).
//   Wave wid stages 16 consecutive rows per gload (1 KB each):
//     set0 rows [wid*16, wid*16+16)      -> region + wid*1024
//     set1 rows [128+wid*16, ...)        -> region + 8192 + wid*1024
// ---------------------------------------------------------------------------

#define STAGE(tn, slotW)                                                        \
  gload16(aSrc0 + (tn) * 32,                 smem + (slotW) + wid * 1024);      \
  gload16(aSrc0 + (size_t)128 * DD + (tn) * 32,                                 \
          smem + (slotW) + 8192 + wid * 1024);                                  \
  gload16(bSrc0 + (tn) * 32,                 smem + (slotW) + 16384 + wid * 1024);\
  gload16(bSrc0 + (size_t)128 * DD + (tn) * 32,                                 \
          smem + (slotW) + 24576 + wid * 1024);

__global__ __launch_bounds__(512, 2) void density_kernel(
    const bf16* __restrict__ Xb, const bf16* __restrict__ Cb,
    const float* __restrict__ xsq, const float* __restrict__ csq,
    const float* __restrict__ w, float* __restrict__ partial) {
  extern __shared__ char smem[];

  const int tid  = (int)threadIdx.x;
  const int lane = tid & 63;
  const int wid  = tid >> 6;    // 0..7
  const int wr   = wid >> 2;    // 0..1 : 128-row half
  const int wcn  = wid & 3;     // 0..3 : 64-col group
  const int lr   = lane & 15;
  const int lc   = lane >> 4;

  // XCD-aware bijective swizzle: grid 1024, 8 XCDs, 128 blocks each.
  const int bid   = (int)blockIdx.x;
  const int swz   = (bid & 7) * 128 + (bid >> 3);
  const int ntile = swz >> 8;
  const int mtile = swz & 255;
  const int rowBase = mtile * BM;
  const int colBase = ntile * BN;

  // staging sources (pre-swizzled chunk; linear DMA dest)
  const int chunkSw = (((lane & 3) ^ ((lane >> 3) & 3)) << 3);
  const bf16* aSrc0 = Xb + (size_t)(rowBase + wid * 16 + (lane >> 2)) * DD + chunkSw;
  const bf16* bSrc0 = Cb + (size_t)(colBase + wid * 16 + (lane >> 2)) * DD + chunkSw;

  // fragment read bases (same XOR on the read side)
  const int rdSw = ((lc ^ ((lr >> 1) & 3)) << 4);
  const int aRd  = (wr * 128 + lr) * 64 + rdSw;            // + mi*1024
  const int bRd  = 16384 + (wcn * 64 + lr) * 64 + rdSw;    // + n*1024

  f32x4 acc[8][4];
#pragma unroll
  for (int m = 0; m < 8; ++m)
#pragma unroll
    for (int n = 0; n < 4; ++n) acc[m][n] = (f32x4){0.f, 0.f, 0.f, 0.f};

  // ---- prologue: stage tiles 0,1,2 into slots 0,1,2 (12 loads/wave) ----
  STAGE(0, 0);
  STAGE(1, SLOT_SZ);
  STAGE(2, 2 * SLOT_SZ);
  asm volatile("s_waitcnt vmcnt(8)" ::: "memory");   // tile 0 landed
  __builtin_amdgcn_s_barrier();

  // ---- main loop: counted vmcnt, prefetch distance 3, never drain ----
#pragma unroll 1
  for (int t = 0; t < NKT; ++t) {
    const int slotR = (t & 3) << 15;

    // stage t+3 first (4 gload_lds; 3-tile window before its vmcnt)
    if (t + 3 < NKT) {
      const int slotW = ((t + 3) & 3) << 15;
      STAGE(t + 3, slotW);
    }

    // B fragments up front (reused by all 8 A-frags)
    bf16x8 bg[4];
#pragma unroll
    for (int n = 0; n < 4; ++n)
      bg[n] = *(const bf16x8*)(smem + slotR + bRd + n * 1024);

    // stream A-frags; compiler inserts counted lgkm waits
    __builtin_amdgcn_s_setprio(1);
#pragma unroll
    for (int mi = 0; mi < 8; ++mi) {
      const bf16x8 a = *(const bf16x8*)(smem + slotR + aRd + mi * 1024);
#pragma unroll
      for (int n = 0; n < 4; ++n)
        acc[mi][n] = __builtin_amdgcn_mfma_f32_16x16x32_bf16(
            a, bg[n], acc[mi][n], 0, 0, 0);
    }
    __builtin_amdgcn_s_setprio(0);

    if (t < NKT - 1) {
      // need tile t+1 landed; outstanding loads beyond it:
      //   t <= NKT-4 : tiles t+2,t+3 in flight -> vmcnt(8)
      //   t == NKT-3 : tile  t+2 (=NKT-1)      -> vmcnt(4)
      //   t == NKT-2 : none                    -> vmcnt(0)
      if (t < NKT - 3) {
        asm volatile("s_waitcnt vmcnt(8)" ::: "memory");
      } else if (t == NKT - 3) {
        asm volatile("s_waitcnt vmcnt(4)" ::: "memory");
      } else {
        asm volatile("s_waitcnt vmcnt(0)" ::: "memory");
      }
      __builtin_amdgcn_s_barrier();
    }
  }

  // ---- epilogue: density partials for this wave's 128x64 output ----
  float xr[8][4];
#pragma unroll
  for (int m = 0; m < 8; ++m)
#pragma unroll
    for (int j = 0; j < 4; ++j)
      xr[m][j] = xsq[rowBase + wr * 128 + m * 16 + lc * 4 + j];

  float rsum[8][4];
#pragma unroll
  for (int m = 0; m < 8; ++m)
#pragma unroll
    for (int j = 0; j < 4; ++j) rsum[m][j] = 0.f;

#pragma unroll
  for (int n = 0; n < 4; ++n) {
    const int gc = colBase + wcn * 64 + n * 16 + lr;
    const float cs = csq[gc];
    const float ww = w[gc];
#pragma unroll
    for (int m = 0; m < 8; ++m)
#pragma unroll
      for (int j = 0; j < 4; ++j) {
        const float sq = xr[m][j] + cs - 2.f * acc[m][n][j];
        rsum[m][j] += ww * __builtin_amdgcn_rcpf(sq);
      }
  }
#pragma unroll
  for (int m = 0; m < 8; ++m)
#pragma unroll
    for (int j = 0; j < 4; ++j) {
      float v = rsum[m][j];
      v += __shfl_xor(v, 1, 64);
      v += __shfl_xor(v, 2, 64);
      v += __shfl_xor(v, 4, 64);
      v += __shfl_xor(v, 8, 64);
      rsum[m][j] = v;
    }

  float* part = (float*)(smem + PART_OFF);   // [4 wcn][256 rows]
  __syncthreads();
  if (lr == 0) {
#pragma unroll
    for (int m = 0; m < 8; ++m)
#pragma unroll
      for (int j = 0; j < 4; ++j)
        part[wcn * 256 + wr * 128 + m * 16 + lc * 4 + j] = rsum[m][j];
  }
  __syncthreads();
  if (tid < BM) {
    const float s = part[tid] + part[256 + tid] + part[512 + tid] + part[768 + tid];
    partial[(size_t)ntile * NR + rowBase + tid] = s;
  }
}

// ---------------------------------------------------------------------------
__global__ __launch_bounds__(256) void reduce_kernel(
    const float* __restrict__ partial, const float* __restrict__ thr,
    float* __restrict__ out) {
  const int n = (int)(blockIdx.x * 256 + threadIdx.x);
  float s = 0.f;
#pragma unroll
  for (int g = 0; g < NPART; ++g) s += partial[(size_t)g * NR + n];
  out[n] = s - thr[0];
}

// ---------------------------------------------------------------------------
extern "C" void kernel_launch(void* const* d_in, const int* in_sizes, int n_in,
                              void* d_out, int out_size, void* d_ws, size_t ws_size,
                              hipStream_t stream) {
  const float* X   = (const float*)d_in[0];
  const float* C   = (const float*)d_in[1];
  const float* var = (const float*)d_in[2];
  const float* pr  = (const float*)d_in[3];
  const float* thr = (const float*)d_in[4];
  float* out = (float*)d_out;

  char* ws = (char*)d_ws;
  bf16* Xb   = (bf16*)(ws);
  bf16* Cb   = (bf16*)(ws + (size_t)NR * DD * 2);
  float* xsq = (float*)(ws + (size_t)NR * DD * 2 + (size_t)KC * DD * 2);
  float* csq = xsq + NR;
  float* w   = csq + KC;
  float* partial = w + KC;   // 4 * 65536 floats = 1 MB

  prep_kernel<<<(NR + KC) / 4, 256, 0, stream>>>(X, C, var, pr, Xb, Cb, xsq, csq, w);
  density_kernel<<<(NR / BM) * NPART, 512, LDS_TOTAL, stream>>>(
      Xb, Cb, xsq, csq, w, partial);
  reduce_kernel<<<NR / 256, 256, 0, stream>>>(partial, thr, out);
}

// Round 3
// 117.595 us; speedup vs baseline: 1.0325x; 1.0325x over previous
//
#include <hip/hip_runtime.h>
#include <stdint.h>

// ---------------------------------------------------------------------------
// DetectorKmeans: out[n] = sum_k (pr[k]*var[k]) / ||X[n]-C[k]||^2  - threshold
// N=65536, K=1024, D=512, all fp32 in/out.
// Round 15: R12/13/14 showed tile time == LDS-pipe time + MFMA-pipe time
// (no overlap: waves drift into lockstep read-bursts then MFMA-bursts).
// Port the m201 8-phase schedule (proven 62% MfmaUtil at THIS geometry):
// each BK=64 tile -> 4 phases of 16 MFMA, phase = {4-8 ds_read, 2 gload_lds,
// barrier, lgkmcnt(0), setprio(1), 16 MFMA, setprio(0), barrier}; vmcnt(0)
// ONCE per tile (phase 3). A staged phases 0-1 (L3 needs cover), B phases
// 2-3 (L2-resident). Geometry/LDS/swizzles/epilogue verbatim R12.
// ---------------------------------------------------------------------------

#define NR 65536
#define KC 1024
#define DD 512

#define BM 256
#define BN 256
#define BK 64
#define NKT (DD / BK)     // 8 K-tiles
#define NPART (KC / BN)   // 4 column panels

#define SLOT_SZ 65536
#define PART_OFF 131072
#define LDS_TOTAL (PART_OFF + 4096)

typedef __bf16 bf16;
typedef __attribute__((ext_vector_type(4))) __bf16 bf16x4;
typedef __attribute__((ext_vector_type(8))) __bf16 bf16x8;
typedef __attribute__((ext_vector_type(4))) float f32x4;

__device__ __forceinline__ void gload16(const void* g, void* l) {
  __builtin_amdgcn_global_load_lds(
      (const __attribute__((address_space(1))) unsigned int*)g,
      (__attribute__((address_space(3))) unsigned int*)l, 16, 0, 0);
}

// ---------------------------------------------------------------------------
__global__ __launch_bounds__(256) void prep_kernel(
    const float* __restrict__ X, const float* __restrict__ C,
    const float* __restrict__ var, const float* __restrict__ pr,
    bf16* __restrict__ Xb, bf16* __restrict__ Cb,
    float* __restrict__ xsq, float* __restrict__ csq, float* __restrict__ w) {
  const int row  = (int)((blockIdx.x * 256 + threadIdx.x) >> 6);
  const int lane = (int)(threadIdx.x & 63);
  const bool isX = row < NR;
  const float* srow = isX ? (X + (size_t)row * DD) : (C + (size_t)(row - NR) * DD);
  bf16* drow = isX ? (Xb + (size_t)row * DD) : (Cb + (size_t)(row - NR) * DD);

  float4 a = reinterpret_cast<const float4*>(srow)[lane];
  float4 b = reinterpret_cast<const float4*>(srow)[64 + lane];
  float s = a.x * a.x + a.y * a.y + a.z * a.z + a.w * a.w +
            b.x * b.x + b.y * b.y + b.z * b.z + b.w * b.w;
#pragma unroll
  for (int off = 1; off < 64; off <<= 1) s += __shfl_xor(s, off, 64);

  bf16x4 va = {(bf16)a.x, (bf16)a.y, (bf16)a.z, (bf16)a.w};
  bf16x4 vb = {(bf16)b.x, (bf16)b.y, (bf16)b.z, (bf16)b.w};
  reinterpret_cast<bf16x4*>(drow)[lane]      = va;
  reinterpret_cast<bf16x4*>(drow)[64 + lane] = vb;

  if (lane == 0) {
    if (isX) {
      xsq[row] = s;
    } else {
      const int k = row - NR;
      csq[k] = s;
      w[k]   = pr[k] * var[k];
    }
  }
}

// ---------------------------------------------------------------------------
// LDS per 64 KB slot (verbatim R12/R6):
//   A half h at slot + h*16384: rows {wr*128 + h*64 + r} at rho = wr*64+r,
//     128 B/row; chunk slot s holds global chunk s ^ (rho&7).
//   B kk at slot + 32768 + kk*16384: 256 cols x 64 B; chunk slot s holds
//     global chunk s ^ ((col>>1)&3).  Pre-swizzled gload source, linear dest.
// ---------------------------------------------------------------------------

#define STAGE_A(h, tn, slotW)                                                   \
  gload16(aSrc0 + (size_t)((h) * 64) * DD + (tn) * 64,                          \
          smem + (slotW) + (h) * 16384 + wid * 1024);                           \
  gload16(aSrc0 + (size_t)((h) * 64 + 128) * DD + (tn) * 64,                    \
          smem + (slotW) + (h) * 16384 + 8192 + wid * 1024);

#define STAGE_B(kk, tn, slotW)                                                  \
  gload16(bSrc0 + (tn) * 64 + (kk) * 32,                                        \
          smem + (slotW) + 32768 + (kk) * 16384 + wid * 1024);                  \
  gload16(bSrc0 + (size_t)128 * DD + (tn) * 64 + (kk) * 32,                     \
          smem + (slotW) + 32768 + (kk) * 16384 + 8192 + wid * 1024);

#define READ_B(dst, kk, base)                                                   \
  _Pragma("unroll") for (int n = 0; n < 4; ++n)                                 \
    dst[n] = *(const bf16x8*)(smem + (base) + 32768 + (kk) * 16384 + bRd +      \
                              n * 1024);

__global__ __launch_bounds__(512, 2) void density_kernel(
    const bf16* __restrict__ Xb, const bf16* __restrict__ Cb,
    const float* __restrict__ xsq, const float* __restrict__ csq,
    const float* __restrict__ w, float* __restrict__ partial) {
  extern __shared__ char smem[];

  const int tid  = (int)threadIdx.x;
  const int lane = tid & 63;
  const int wid  = tid >> 6;    // 0..7
  const int wr   = wid >> 2;    // 0..1 : 128-row half
  const int wcn  = wid & 3;     // 0..3 : 64-col group
  const int lr   = lane & 15;
  const int lc   = lane >> 4;

  // XCD-aware bijective swizzle: grid 1024, 8 XCDs, 128 blocks each.
  const int bid   = (int)blockIdx.x;
  const int swz   = (bid & 7) * 128 + (bid >> 3);
  const int ntile = swz >> 8;
  const int mtile = swz & 255;
  const int rowBase = mtile * BM;
  const int colBase = ntile * BN;

  // staging sources (pre-swizzled chunk; linear DMA dest) — verbatim R12
  const bf16* aSrc0 = Xb + (size_t)(rowBase + wid * 8 + (lane >> 3)) * DD +
                      (((lane & 7) ^ (lane >> 3)) << 3);
  const bf16* bSrc0 = Cb + (size_t)(colBase + wid * 16 + (lane >> 2)) * DD +
                      ((((lane & 3) ^ ((lane >> 3) & 3))) << 3);

  // fragment read bases (same XOR on the read side) — verbatim R12
  const int aRd  = (wr * 64 + lr) * 128;
  const int aSw0 = ((lc ^ (lr & 7)) << 4);
  const int aSw1 = (((4 | lc) ^ (lr & 7)) << 4);
  const int bRd  = (wcn * 64 + lr) * 64 + ((lc ^ ((lr >> 1) & 3)) << 4);

  f32x4 acc[8][4];
#pragma unroll
  for (int m = 0; m < 8; ++m)
#pragma unroll
    for (int n = 0; n < 4; ++n) acc[m][n] = (f32x4){0.f, 0.f, 0.f, 0.f};

  // ---- prologue: stage tile 0 into slot 0 ----
  STAGE_A(0, 0, 0);
  STAGE_B(0, 0, 0);
  STAGE_A(1, 0, 0);
  STAGE_B(1, 0, 0);
  asm volatile("s_waitcnt vmcnt(0)");
  __builtin_amdgcn_s_barrier();

  // ---- main loop: 4 phases per K-tile, barrier pair per phase ----
#pragma unroll 1
  for (int t = 0; t < NKT; ++t) {
    const int slotR = (t & 1) << 16;
    const int slotW = slotR ^ SLOT_SZ;
    const int tn = t + 1;
    const bool st = tn < NKT;

    bf16x8 bgK0[4], bgK1[4];

#pragma unroll
    for (int p = 0; p < 4; ++p) {
      const int h  = p >> 1;    // m-half
      const int kk = p & 1;     // k-half

      // ---- read segment (before leading barrier) ----
      if (p == 0) { READ_B(bgK0, 0, slotR); }
      if (p == 1) { READ_B(bgK1, 1, slotR); }

      bf16x8 af[4];
#pragma unroll
      for (int mi = 0; mi < 4; ++mi)
        af[mi] = *(const bf16x8*)(smem + slotR + h * 16384 + aRd + mi * 2048 +
                                  (kk ? aSw1 : aSw0));

      // ---- stage segment: 2 gload_lds per phase (A early: L3 latency) ----
      if (st) {
        if (p == 0) { STAGE_A(0, tn, slotW); }
        if (p == 1) { STAGE_A(1, tn, slotW); }
        if (p == 2) { STAGE_B(0, tn, slotW); }
        if (p == 3) { STAGE_B(1, tn, slotW); }
      }

      __builtin_amdgcn_s_barrier();
      asm volatile("s_waitcnt lgkmcnt(0)" ::: "memory");

      // ---- MFMA cluster: 4 mi x 4 n for this (h, kk) ----
      __builtin_amdgcn_s_setprio(1);
#pragma unroll
      for (int mi = 0; mi < 4; ++mi) {
#pragma unroll
        for (int n = 0; n < 4; ++n) {
          if (kk == 0)
            acc[h * 4 + mi][n] = __builtin_amdgcn_mfma_f32_16x16x32_bf16(
                af[mi], bgK0[n], acc[h * 4 + mi][n], 0, 0, 0);
          else
            acc[h * 4 + mi][n] = __builtin_amdgcn_mfma_f32_16x16x32_bf16(
                af[mi], bgK1[n], acc[h * 4 + mi][n], 0, 0, 0);
        }
      }
      __builtin_amdgcn_s_setprio(0);

      // vmcnt ONCE per tile, at the tile's last phase (T4: never per-phase)
      if (p == 3 && st) asm volatile("s_waitcnt vmcnt(0)" ::: "memory");
      if (p < 3 || st) __builtin_amdgcn_s_barrier();
    }
  }

  // ---- epilogue: density partials for this wave's 128x64 output ----
  float xr[8][4];
#pragma unroll
  for (int m = 0; m < 8; ++m)
#pragma unroll
    for (int j = 0; j < 4; ++j)
      xr[m][j] = xsq[rowBase + wr * 128 + m * 16 + lc * 4 + j];

  float rsum[8][4];
#pragma unroll
  for (int m = 0; m < 8; ++m)
#pragma unroll
    for (int j = 0; j < 4; ++j) rsum[m][j] = 0.f;

#pragma unroll
  for (int n = 0; n < 4; ++n) {
    const int gc = colBase + wcn * 64 + n * 16 + lr;
    const float cs = csq[gc];
    const float ww = w[gc];
#pragma unroll
    for (int m = 0; m < 8; ++m)
#pragma unroll
      for (int j = 0; j < 4; ++j) {
        const float sq = xr[m][j] + cs - 2.f * acc[m][n][j];
        rsum[m][j] += ww * __builtin_amdgcn_rcpf(sq);
      }
  }
#pragma unroll
  for (int m = 0; m < 8; ++m)
#pragma unroll
    for (int j = 0; j < 4; ++j) {
      float v = rsum[m][j];
      v += __shfl_xor(v, 1, 64);
      v += __shfl_xor(v, 2, 64);
      v += __shfl_xor(v, 4, 64);
      v += __shfl_xor(v, 8, 64);
      rsum[m][j] = v;
    }

  float* part = (float*)(smem + PART_OFF);   // [4 wcn][256 rows]
  __syncthreads();
  if (lr == 0) {
#pragma unroll
    for (int m = 0; m < 8; ++m)
#pragma unroll
      for (int j = 0; j < 4; ++j)
        part[wcn * 256 + wr * 128 + m * 16 + lc * 4 + j] = rsum[m][j];
  }
  __syncthreads();
  if (tid < BM) {
    const float s = part[tid] + part[256 + tid] + part[512 + tid] + part[768 + tid];
    partial[(size_t)ntile * NR + rowBase + tid] = s;
  }
}

// ---------------------------------------------------------------------------
__global__ __launch_bounds__(256) void reduce_kernel(
    const float* __restrict__ partial, const float* __restrict__ thr,
    float* __restrict__ out) {
  const int n = (int)(blockIdx.x * 256 + threadIdx.x);
  float s = 0.f;
#pragma unroll
  for (int g = 0; g < NPART; ++g) s += partial[(size_t)g * NR + n];
  out[n] = s - thr[0];
}

// ---------------------------------------------------------------------------
extern "C" void kernel_launch(void* const* d_in, const int* in_sizes, int n_in,
                              void* d_out, int out_size, void* d_ws, size_t ws_size,
                              hipStream_t stream) {
  const float* X   = (const float*)d_in[0];
  const float* C   = (const float*)d_in[1];
  const float* var = (const float*)d_in[2];
  const float* pr  = (const float*)d_in[3];
  const float* thr = (const float*)d_in[4];
  float* out = (float*)d_out;

  char* ws = (char*)d_ws;
  bf16* Xb   = (bf16*)(ws);
  bf16* Cb   = (bf16*)(ws + (size_t)NR * DD * 2);
  float* xsq = (float*)(ws + (size_t)NR * DD * 2 + (size_t)KC * DD * 2);
  float* csq = xsq + NR;
  float* w   = csq + KC;
  float* partial = w + KC;   // 4 * 65536 floats = 1 MB

  prep_kernel<<<(NR + KC) / 4, 256, 0, stream>>>(X, C, var, pr, Xb, Cb, xsq, csq, w);
  density_kernel<<<(NR / BM) * NPART, 512, LDS_TOTAL, stream>>>(
      Xb, Cb, xsq, csq, w, partial);
  reduce_kernel<<<NR / 256, 256, 0, stream>>>(partial, thr, out);
}